// Round 1
// baseline (2200.964 us; speedup 1.0000x reference)
//
#include <hip/hip_runtime.h>

#define TT 32768   // B*S tokens
#define DD 512
#define HH 2048
#define EE 8
#define TILES 512  // TT/64

typedef unsigned short u16;
using short8  = __attribute__((ext_vector_type(8))) short;
using floatx4 = __attribute__((ext_vector_type(4))) float;

__device__ __forceinline__ u16 f2bf(float f) {
  unsigned u = __float_as_uint(f);
  u += 0x7FFFu + ((u >> 16) & 1u);   // RNE; inputs are finite
  return (u16)(u >> 16);
}

// ---------------- x fp32 -> bf16 ----------------
__global__ void convert_x_kernel(const float* __restrict__ x, u16* __restrict__ xb, int n4) {
  int i = blockIdx.x * 256 + threadIdx.x;
  if (i >= n4) return;
  float4 v = ((const float4*)x)[i];
  ushort4 o;
  o.x = f2bf(v.x); o.y = f2bf(v.y); o.z = f2bf(v.z); o.w = f2bf(v.w);
  ((ushort4*)xb)[i] = o;
}

// ------------- transpose fp32 [E][R][C] -> bf16 [E][C][R] -------------
__global__ void transpose_bf16(const float* __restrict__ in, u16* __restrict__ out, int R, int C) {
  __shared__ float tile[32][33];
  int e = blockIdx.z;
  const float* src = in + (size_t)e * R * C;
  u16* dst = out + (size_t)e * R * C;
  int tx = threadIdx.x, ty = threadIdx.y;
  int c0 = blockIdx.x * 32, r0 = blockIdx.y * 32;
#pragma unroll
  for (int i = 0; i < 32; i += 8)
    tile[ty + i][tx] = src[(size_t)(r0 + ty + i) * C + c0 + tx];
  __syncthreads();
#pragma unroll
  for (int i = 0; i < 32; i += 8)
    dst[(size_t)(c0 + ty + i) * R + r0 + tx] = f2bf(tile[tx][ty + i]);
}

// ---------------- router: one wave per token ----------------
__global__ void router_kernel(const float* __restrict__ x, const float* __restrict__ noise,
                              const float* __restrict__ Wg, const float* __restrict__ bg,
                              const float* __restrict__ Wn, const float* __restrict__ bn,
                              int* __restrict__ counts, int* __restrict__ lists,
                              float* __restrict__ gates) {
  const int t = (blockIdx.x * blockDim.x + threadIdx.x) >> 6;
  const int lane = threadIdx.x & 63;
  if (t >= TT) return;
  const float4* xr = (const float4*)(x + (size_t)t * DD) + lane * 2;
  float4 xa = xr[0], xbv = xr[1];
  float xv[8] = {xa.x, xa.y, xa.z, xa.w, xbv.x, xbv.y, xbv.z, xbv.w};
  float pg[8], pn[8];
#pragma unroll
  for (int e = 0; e < 8; ++e) { pg[e] = 0.f; pn[e] = 0.f; }
  const float4* wg4 = (const float4*)(Wg + lane * 64);
  const float4* wn4 = (const float4*)(Wn + lane * 64);
#pragma unroll
  for (int j = 0; j < 8; ++j) {
    float xj = xv[j];
    float4 a = wg4[2 * j], b = wg4[2 * j + 1];
    pg[0] += xj * a.x; pg[1] += xj * a.y; pg[2] += xj * a.z; pg[3] += xj * a.w;
    pg[4] += xj * b.x; pg[5] += xj * b.y; pg[6] += xj * b.z; pg[7] += xj * b.w;
    a = wn4[2 * j]; b = wn4[2 * j + 1];
    pn[0] += xj * a.x; pn[1] += xj * a.y; pn[2] += xj * a.z; pn[3] += xj * a.w;
    pn[4] += xj * b.x; pn[5] += xj * b.y; pn[6] += xj * b.z; pn[7] += xj * b.w;
  }
#pragma unroll
  for (int off = 32; off; off >>= 1) {
#pragma unroll
    for (int e = 0; e < 8; ++e) {
      pg[e] += __shfl_xor(pg[e], off);
      pn[e] += __shfl_xor(pn[e], off);
    }
  }
  if (lane == 0) {
    float noisy[8];
#pragma unroll
    for (int e = 0; e < 8; ++e) {
      float nl = pn[e] + bn[e];
      float sp = (nl > 20.f) ? nl : log1pf(expf(nl));
      noisy[e] = pg[e] + bg[e] + noise[(size_t)t * EE + e] * sp;
    }
    int i0 = 0; float v0 = noisy[0];
#pragma unroll
    for (int e = 1; e < 8; ++e) if (noisy[e] > v0) { v0 = noisy[e]; i0 = e; }
    int i1 = -1; float v1 = -3.4e38f;
#pragma unroll
    for (int e = 0; e < 8; ++e) if (e != i0 && noisy[e] > v1) { v1 = noisy[e]; i1 = e; }
    float ed = expf(v1 - v0);
    float inv = 1.f / (1.f + ed);
    int s0 = atomicAdd(counts + i0, 1);
    lists[i0 * TT + s0] = t; gates[i0 * TT + s0] = inv;
    int s1 = atomicAdd(counts + i1, 1);
    lists[i1 * TT + s1] = t; gates[i1 * TT + s1] = ed * inv;
  }
}

// ---------------- fused expert MLP ----------------
// LDS map (bytes): Xs 0..65536 | W1s 65536..81920 | W2s 81920..147456 | Hs 147456..155648
//                  tok 155648..155904 | gate 155904..156160   (total 156160 <= 160 KiB)
#define XS_OFF   0
#define W1S_OFF  65536
#define W2S_OFF  81920
#define HS_OFF   147456
#define TOK_OFF  155648
#define GATE_OFF 155904

__global__ __launch_bounds__(512, 1)
void moe_mlp(const u16* __restrict__ xb, const u16* __restrict__ w1t,
             const u16* __restrict__ w2t, const float* __restrict__ b1,
             const float* __restrict__ b2, const int* __restrict__ counts,
             const int* __restrict__ lists, const float* __restrict__ gates,
             float* __restrict__ out) {
  __shared__ __align__(16) char smem[156160];
  short8* xs  = (short8*)(smem + XS_OFF);
  short8* w1s = (short8*)(smem + W1S_OFF);
  short8* w2s = (short8*)(smem + W2S_OFF);
  short8* hs  = (short8*)(smem + HS_OFF);
  int*   tok_s  = (int*)(smem + TOK_OFF);
  float* gate_s = (float*)(smem + GATE_OFF);

  const int e = blockIdx.x >> 9;
  const int tile = blockIdx.x & 511;
  const int cnt = counts[e];
  if (tile * 64 >= cnt) return;

  const int tid = threadIdx.x;
  const int lane = tid & 63;
  const int w = tid >> 6;           // 8 waves
  const int col = lane & 15;
  const int quad = lane >> 4;

  if (tid < 64) {
    int idx = tile * 64 + tid;
    int tok = -1; float g = 0.f;
    if (idx < cnt) { tok = lists[e * TT + idx]; g = gates[e * TT + idx]; }
    tok_s[tid] = tok; gate_s[tid] = g;
  }
  __syncthreads();

  // stage Xs fragment-packed: slot c = (mtile*16+kblock)*64 + (m16|quad<<4) == c linear
#pragma unroll
  for (int it = 0; it < 8; ++it) {
    int c = it * 512 + tid;
    int m16 = c & 15, d8 = (c >> 4) & 63, mt = c >> 10;
    int tok = tok_s[mt * 16 + m16];
    short8 v = {0, 0, 0, 0, 0, 0, 0, 0};
    if (tok >= 0) v = *(const short8*)(xb + ((size_t)tok * DD + d8 * 8));
    xs[c] = v;
  }

  floatx4 acc2[16];
#pragma unroll
  for (int i = 0; i < 16; ++i) acc2[i] = (floatx4){0.f, 0.f, 0.f, 0.f};

  const int htile = w & 3, mhalf = w >> 2;  // layer-1 partition: H^T[64h][64m]
  const int mtile2 = w & 3, nhalf = w >> 2; // layer-2 partition: Y[64m][512n]

  for (int hc = 0; hc < 32; ++hc) {
    floatx4 acc1[2];
    acc1[0] = (floatx4){0.f, 0.f, 0.f, 0.f};
    acc1[1] = (floatx4){0.f, 0.f, 0.f, 0.f};
    // ----- layer 1: H^T[h][m] = sum_d W1T[h][d] * X[m][d] -----
    for (int dc = 0; dc < 4; ++dc) {
      __syncthreads();
      { // stage W1s tile [64h][128d], 512 chunks of 32B
        int c = tid;
        int h16 = c & 15, d16 = (c >> 4) & 7, nt = (c >> 7) & 3;
        const short8* gp = (const short8*)(w1t +
            ((size_t)(e * HH + hc * 64 + nt * 16 + h16) * DD + dc * 128 + d16 * 16));
        short8 v0 = gp[0], v1 = gp[1];
        int a0 = nt * 256 + (d16 >> 1) * 64 + (d16 & 1) * 32 + h16;
        w1s[a0] = v0; w1s[a0 + 16] = v1;
      }
      __syncthreads();
#pragma unroll
      for (int ks = 0; ks < 4; ++ks) {
        short8 af = w1s[(htile * 4 + ks) * 64 + lane];  // A: rows h, k-contig
#pragma unroll
        for (int mt = 0; mt < 2; ++mt) {
          short8 bf = xs[((mhalf * 2 + mt) * 16 + dc * 4 + ks) * 64 + lane]; // B: cols m
          acc1[mt] = __builtin_amdgcn_mfma_f32_16x16x32_bf16(af, bf, acc1[mt], 0, 0, 0);
        }
      }
    }
    // epilogue: +b1, relu, pack 4 consecutive h per lane -> Hs (A-layout [64m][64h])
    {
      int hloc = htile * 16 + quad * 4;  // h of reg r = hloc + r (within this h-chunk)
      float b1v[4];
#pragma unroll
      for (int r = 0; r < 4; ++r) b1v[r] = b1[e * HH + hc * 64 + hloc + r];
#pragma unroll
      for (int nt = 0; nt < 2; ++nt) {
        int m = mhalf * 32 + nt * 16 + col;
        unsigned long long pk = 0;
#pragma unroll
        for (int r = 0; r < 4; ++r) {
          float f = acc1[nt][r] + b1v[r];
          f = fmaxf(f, 0.f);
          pk |= (unsigned long long)f2bf(f) << (16 * r);
        }
        int kblock = htile >> 1;
        int quadp = (htile & 1) * 2 + (quad >> 1);
        *(unsigned long long*)((char*)hs +
            (((m >> 4) * 2 + kblock) * 64 + ((m & 15) + 16 * quadp)) * 16 + (quad & 1) * 8) = pk;
      }
    }
    __syncthreads();
    // stage W2s [512n][64k], 2048 chunks of 32B
#pragma unroll
    for (int it = 0; it < 4; ++it) {
      int c = it * 512 + tid;
      int n16 = c & 15, hq = (c >> 4) & 3, nt = (c >> 6) & 31;
      const short8* gp = (const short8*)(w2t +
          ((size_t)(e * DD + nt * 16 + n16) * HH + hc * 64 + hq * 16));
      short8 v0 = gp[0], v1 = gp[1];
      int a0 = nt * 128 + (hq >> 1) * 64 + (hq & 1) * 32 + n16;
      w2s[a0] = v0; w2s[a0 + 16] = v1;
    }
    __syncthreads();
    // ----- layer 2: Y[m][n] += sum_h Hs[m][h] * W2T[n][h] -----
#pragma unroll
    for (int ks = 0; ks < 2; ++ks) {
      short8 af = hs[(mtile2 * 2 + ks) * 64 + lane];
#pragma unroll
      for (int nt = 0; nt < 16; ++nt) {
        short8 bf = w2s[((nhalf * 16 + nt) * 2 + ks) * 64 + lane];
        acc2[nt] = __builtin_amdgcn_mfma_f32_16x16x32_bf16(af, bf, acc2[nt], 0, 0, 0);
      }
    }
  }

  // store: scale by gate, +b2, atomic scatter-add (each out elem gets exactly 2 adds)
#pragma unroll
  for (int r = 0; r < 4; ++r) {
    int m = mtile2 * 16 + quad * 4 + r;
    int tok = tok_s[m];
    if (tok < 0) continue;
    float g = gate_s[m];
    float* orow = out + (size_t)tok * DD;
#pragma unroll
    for (int nt = 0; nt < 16; ++nt) {
      int n = nhalf * 256 + nt * 16 + col;
      atomicAdd(orow + n, g * (acc2[nt][r] + b2[e * DD + n]));
    }
  }
}

extern "C" void kernel_launch(void* const* d_in, const int* in_sizes, int n_in,
                              void* d_out, int out_size, void* d_ws, size_t ws_size,
                              hipStream_t stream) {
  const float* x     = (const float*)d_in[0];
  const float* noise = (const float*)d_in[1];
  const float* Wg    = (const float*)d_in[2];
  const float* bg    = (const float*)d_in[3];
  const float* Wn    = (const float*)d_in[4];
  const float* bn    = (const float*)d_in[5];
  const float* W1    = (const float*)d_in[6];
  const float* b1    = (const float*)d_in[7];
  const float* W2    = (const float*)d_in[8];
  const float* b2    = (const float*)d_in[9];
  float* out = (float*)d_out;
  char* ws = (char*)d_ws;
  // ws layout (needs ~69.2 MB):
  u16* w1t   = (u16*)(ws + 0);          // [E][H][D] bf16, 16 MB
  u16* w2t   = (u16*)(ws + 16777216);   // [E][D][H] bf16, 16 MB
  u16* xb    = (u16*)(ws + 33554432);   // [T][D] bf16, 32 MB
  int* counts  = (int*)(ws + 67108864); // [E]
  int* lists   = (int*)(ws + 67108928); // [E][T]
  float* gatesp = (float*)(ws + 68157504); // [E][T]

  hipMemsetAsync(out, 0, (size_t)TT * DD * 4, stream);
  hipMemsetAsync(counts, 0, EE * 4, stream);
  convert_x_kernel<<<TT * DD / 4 / 256, 256, 0, stream>>>(x, xb, TT * DD / 4);
  transpose_bf16<<<dim3(HH / 32, DD / 32, EE), dim3(32, 8), 0, stream>>>(W1, w1t, DD, HH);
  transpose_bf16<<<dim3(DD / 32, HH / 32, EE), dim3(32, 8), 0, stream>>>(W2, w2t, HH, DD);
  router_kernel<<<TT / 4, 256, 0, stream>>>(x, noise, Wg, bg, Wn, bn, counts, lists, gatesp);
  moe_mlp<<<EE * TILES, 512, 0, stream>>>(xb, w1t, w2t, b1, b2, counts, lists, gatesp, out);
}

// Round 3
// 880.677 us; speedup vs baseline: 2.4992x; 2.4992x over previous
//
#include <hip/hip_runtime.h>

#define TT 32768   // B*S tokens
#define DD 512
#define HH 2048
#define EE 8
#define HC 1024    // h-chunk: H buffer is [2*TT+128][HC] bf16 per chunk pass

typedef unsigned short u16;
typedef unsigned int u32;
typedef unsigned long long u64;
using short8  = __attribute__((ext_vector_type(8))) short;
using floatx4 = __attribute__((ext_vector_type(4))) float;

__device__ __forceinline__ u16 f2bf(float f) {
  unsigned u = __float_as_uint(f);
  u += 0x7FFFu + ((u >> 16) & 1u);   // RNE; inputs are finite
  return (u16)(u >> 16);
}

// async global->LDS, 16B per lane; lds dest is wave-uniform base + lane*16
__device__ __forceinline__ void gl2lds16(const u16* g, char* l) {
  __builtin_amdgcn_global_load_lds(
      (const __attribute__((address_space(1))) u32*)(const void*)g,
      (__attribute__((address_space(3))) u32*)(void*)l, 16, 0, 0);
}

// ---------------- x fp32 -> bf16 ----------------
__global__ void convert_x_kernel(const float* __restrict__ x, u16* __restrict__ xb, int n4) {
  int i = blockIdx.x * 256 + threadIdx.x;
  if (i >= n4) return;
  float4 v = ((const float4*)x)[i];
  ushort4 o;
  o.x = f2bf(v.x); o.y = f2bf(v.y); o.z = f2bf(v.z); o.w = f2bf(v.w);
  ((ushort4*)xb)[i] = o;
}

// ------------- transpose fp32 [E][R][C] -> bf16 [E][C][R] -------------
__global__ void transpose_bf16(const float* __restrict__ in, u16* __restrict__ out, int R, int C) {
  __shared__ float tile[32][33];
  int e = blockIdx.z;
  const float* src = in + (size_t)e * R * C;
  u16* dst = out + (size_t)e * R * C;
  int tx = threadIdx.x, ty = threadIdx.y;
  int c0 = blockIdx.x * 32, r0 = blockIdx.y * 32;
#pragma unroll
  for (int i = 0; i < 32; i += 8)
    tile[ty + i][tx] = src[(size_t)(r0 + ty + i) * C + c0 + tx];
  __syncthreads();
#pragma unroll
  for (int i = 0; i < 32; i += 8)
    dst[(size_t)(c0 + ty + i) * R + r0 + tx] = f2bf(tile[tx][ty + i]);
}

// ---------------- router pass 1: one wave per token, NO global atomics ----------------
__global__ void router_topk(const float* __restrict__ x, const float* __restrict__ noise,
                            const float* __restrict__ Wg, const float* __restrict__ bg,
                            const float* __restrict__ Wn, const float* __restrict__ bn,
                            int* __restrict__ topk_i, float* __restrict__ topk_g0,
                            float* __restrict__ topk_g1) {
  const int t = (blockIdx.x * blockDim.x + threadIdx.x) >> 6;
  const int lane = threadIdx.x & 63;
  if (t >= TT) return;
  const float4* xr = (const float4*)(x + (size_t)t * DD) + lane * 2;
  float4 xa = xr[0], xbv = xr[1];
  float xv[8] = {xa.x, xa.y, xa.z, xa.w, xbv.x, xbv.y, xbv.z, xbv.w};
  float pg[8], pn[8];
#pragma unroll
  for (int e = 0; e < 8; ++e) { pg[e] = 0.f; pn[e] = 0.f; }
  const float4* wg4 = (const float4*)(Wg + lane * 64);
  const float4* wn4 = (const float4*)(Wn + lane * 64);
#pragma unroll
  for (int j = 0; j < 8; ++j) {
    float xj = xv[j];
    float4 a = wg4[2 * j], b = wg4[2 * j + 1];
    pg[0] += xj * a.x; pg[1] += xj * a.y; pg[2] += xj * a.z; pg[3] += xj * a.w;
    pg[4] += xj * b.x; pg[5] += xj * b.y; pg[6] += xj * b.z; pg[7] += xj * b.w;
    a = wn4[2 * j]; b = wn4[2 * j + 1];
    pn[0] += xj * a.x; pn[1] += xj * a.y; pn[2] += xj * a.z; pn[3] += xj * a.w;
    pn[4] += xj * b.x; pn[5] += xj * b.y; pn[6] += xj * b.z; pn[7] += xj * b.w;
  }
#pragma unroll
  for (int off = 32; off; off >>= 1) {
#pragma unroll
    for (int e = 0; e < 8; ++e) {
      pg[e] += __shfl_xor(pg[e], off);
      pn[e] += __shfl_xor(pn[e], off);
    }
  }
  if (lane == 0) {
    float noisy[8];
#pragma unroll
    for (int e = 0; e < 8; ++e) {
      float nl = pn[e] + bn[e];
      float sp = (nl > 20.f) ? nl : log1pf(expf(nl));
      noisy[e] = pg[e] + bg[e] + noise[(size_t)t * EE + e] * sp;
    }
    int i0 = 0; float v0 = noisy[0];
#pragma unroll
    for (int e = 1; e < 8; ++e) if (noisy[e] > v0) { v0 = noisy[e]; i0 = e; }
    int i1 = -1; float v1 = -3.4e38f;
#pragma unroll
    for (int e = 0; e < 8; ++e) if (e != i0 && noisy[e] > v1) { v1 = noisy[e]; i1 = e; }
    float ed = expf(v1 - v0);
    float inv = 1.f / (1.f + ed);
    topk_i[t] = i0 | (i1 << 8);
    topk_g0[t] = inv;
    topk_g1[t] = ed * inv;
  }
}

// ---------------- router pass 2: bin tokens; 8 global atomics per 256 tokens ----------------
__global__ void router_bin(const int* __restrict__ topk_i, const float* __restrict__ tg0,
                           const float* __restrict__ tg1, int* __restrict__ counts,
                           int* __restrict__ lists, float* __restrict__ gates) {
  __shared__ int hist[EE], base_s[EE];
  int t = blockIdx.x * 256 + threadIdx.x;
  if (threadIdx.x < EE) hist[threadIdx.x] = 0;
  __syncthreads();
  int p = topk_i[t];
  int i0 = p & 255, i1 = p >> 8;
  int r0 = atomicAdd(&hist[i0], 1);
  int r1 = atomicAdd(&hist[i1], 1);
  __syncthreads();
  if (threadIdx.x < EE)
    base_s[threadIdx.x] = atomicAdd(&counts[threadIdx.x], hist[threadIdx.x]);
  __syncthreads();
  int s0 = base_s[i0] + r0, s1 = base_s[i1] + r1;
  lists[i0 * TT + s0] = t; gates[i0 * TT + s0] = tg0[t];
  lists[i1 * TT + s1] = t; gates[i1 * TT + s1] = tg1[t];
}

// ============ PASS 1: H_chunk = relu(X_gathered @ W1[:, hoff:hoff+HC] + b1)  (bf16) ============
// m97 structure: 128x128 tile, BK=64, 4 waves x (64x64), XOR-swizzled 16B LDS chunks.
__global__ __launch_bounds__(256, 2)
void pass1_gemm(const u16* __restrict__ xb, const u16* __restrict__ w1t,
                const float* __restrict__ b1, const int* __restrict__ counts,
                const int* __restrict__ lists, u16* __restrict__ H, int hoff) {
  __shared__ __align__(16) char lds[32768];
  char* ldsA = lds;           // W1^T tile [128 h][64 k]
  char* ldsB = lds + 16384;   // X tile    [128 m][64 k]
  const int e = blockIdx.x & 7;           // expert -> XCD pin for L2 locality
  const int mseed = blockIdx.x >> 3;      // 0..79
  const int ntile = blockIdx.y;           // 0..HC/128-1
  const int cnt = counts[e];
  int eOff = 0;
#pragma unroll
  for (int j = 0; j < EE; ++j) eOff += (j < e) ? counts[j] : 0;
  const int tid = threadIdx.x, lane = tid & 63, w = tid >> 6;
  const int col16 = lane & 15, quad = lane >> 4;
  const int hh = w & 1, mh = w >> 1;

  int rowi[4], kqi[4];
  const u16* wptr[4];
#pragma unroll
  for (int i = 0; i < 4; ++i) {
    int c = tid + i * 256;
    rowi[i] = c >> 3;
    kqi[i] = (c & 7) ^ (rowi[i] & 7);
    wptr[i] = w1t + (size_t)(e * HH + hoff + ntile * 128 + rowi[i]) * DD + kqi[i] * 8;
  }

  for (int mtile = mseed; mtile * 128 < cnt; mtile += 80) {
    const u16* xptr[4];
#pragma unroll
    for (int i = 0; i < 4; ++i) {
      int idx = mtile * 128 + rowi[i];
      int tok = (idx < cnt) ? lists[e * TT + idx] : 0;
      xptr[i] = xb + (size_t)tok * DD + kqi[i] * 8;
    }
    floatx4 acc[4][4];
#pragma unroll
    for (int a = 0; a < 4; ++a)
#pragma unroll
      for (int b = 0; b < 4; ++b) acc[a][b] = (floatx4){0.f, 0.f, 0.f, 0.f};

    for (int kc = 0; kc < 8; ++kc) {      // K = 512, BK = 64
      __syncthreads();
#pragma unroll
      for (int i = 0; i < 4; ++i) {
        int off = (tid + i * 256) * 16;
        gl2lds16(wptr[i] + kc * 64, ldsA + off);
        gl2lds16(xptr[i] + kc * 64, ldsB + off);
      }
      __syncthreads();
#pragma unroll
      for (int ks = 0; ks < 2; ++ks) {
        short8 af[4], bf[4];
#pragma unroll
        for (int t4 = 0; t4 < 4; ++t4) {
          int rA = hh * 64 + t4 * 16 + col16;
          af[t4] = *(const short8*)(ldsA + (rA * 8 + ((ks * 4 + quad) ^ (rA & 7))) * 16);
          int rB = mh * 64 + t4 * 16 + col16;
          bf[t4] = *(const short8*)(ldsB + (rB * 8 + ((ks * 4 + quad) ^ (rB & 7))) * 16);
        }
#pragma unroll
        for (int ht = 0; ht < 4; ++ht)
#pragma unroll
          for (int mt = 0; mt < 4; ++mt)
            acc[ht][mt] = __builtin_amdgcn_mfma_f32_16x16x32_bf16(af[ht], bf[mt], acc[ht][mt], 0, 0, 0);
      }
    }
    // epilogue: +b1, relu, bf16 pack (4 consecutive h per lane -> b64 store into H chunk)
#pragma unroll
    for (int ht = 0; ht < 4; ++ht) {
      int hloc = ntile * 128 + hh * 64 + ht * 16 + quad * 4;   // within chunk
      float b1v[4];
#pragma unroll
      for (int r = 0; r < 4; ++r) b1v[r] = b1[e * HH + hoff + hloc + r];
#pragma unroll
      for (int mt = 0; mt < 4; ++mt) {
        int gm = mtile * 128 + mh * 64 + mt * 16 + col16;
        if (gm < cnt) {
          u64 pk = 0;
#pragma unroll
          for (int r = 0; r < 4; ++r) {
            float f = fmaxf(acc[ht][mt][r] + b1v[r], 0.f);
            pk |= (u64)f2bf(f) << (16 * r);
          }
          *(u64*)(H + (size_t)(eOff + gm) * HC + hloc) = pk;
        }
      }
    }
  }
}

// ============ PASS 2: out += gate * (H_chunk @ W2[hoff:hoff+HC, :] [+ b2]) ============
__global__ __launch_bounds__(256, 2)
void pass2_gemm(const u16* __restrict__ H, const u16* __restrict__ w2t,
                const float* __restrict__ b2, const int* __restrict__ counts,
                const int* __restrict__ lists, const float* __restrict__ gates,
                float* __restrict__ out, int hoff, int addb2) {
  __shared__ __align__(16) char lds[32768];
  char* ldsA = lds;           // H tile   [128 m][64 k]
  char* ldsB = lds + 16384;   // W2^T tile[128 d][64 k]
  const int e = blockIdx.x & 7;
  const int mseed = blockIdx.x >> 3;
  const int ntile = blockIdx.y;           // 0..3 (d block of 128)
  const int cnt = counts[e];
  int eOff = 0;
#pragma unroll
  for (int j = 0; j < EE; ++j) eOff += (j < e) ? counts[j] : 0;
  const int tid = threadIdx.x, lane = tid & 63, w = tid >> 6;
  const int col16 = lane & 15, quad = lane >> 4;
  const int mh = w & 1, dh = w >> 1;

  int rowi[4], kqi[4];
  const u16* wptr[4];
#pragma unroll
  for (int i = 0; i < 4; ++i) {
    int c = tid + i * 256;
    rowi[i] = c >> 3;
    kqi[i] = (c & 7) ^ (rowi[i] & 7);
    wptr[i] = w2t + (size_t)(e * DD + ntile * 128 + rowi[i]) * HH + hoff + kqi[i] * 8;
  }

  for (int mtile = mseed; mtile * 128 < cnt; mtile += 80) {
    const u16* hptr[4];
#pragma unroll
    for (int i = 0; i < 4; ++i)
      hptr[i] = H + (size_t)(eOff + mtile * 128 + rowi[i]) * HC + kqi[i] * 8;  // pad rows exist

    floatx4 acc[4][4];
#pragma unroll
    for (int a = 0; a < 4; ++a)
#pragma unroll
      for (int b = 0; b < 4; ++b) acc[a][b] = (floatx4){0.f, 0.f, 0.f, 0.f};

    for (int kc = 0; kc < HC / 64; ++kc) {   // K = HC = 1024, BK = 64
      __syncthreads();
#pragma unroll
      for (int i = 0; i < 4; ++i) {
        int off = (tid + i * 256) * 16;
        gl2lds16(hptr[i] + kc * 64, ldsA + off);
        gl2lds16(wptr[i] + kc * 64, ldsB + off);
      }
      __syncthreads();
#pragma unroll
      for (int ks = 0; ks < 2; ++ks) {
        short8 af[4], bf[4];
#pragma unroll
        for (int t4 = 0; t4 < 4; ++t4) {
          int rA = mh * 64 + t4 * 16 + col16;
          af[t4] = *(const short8*)(ldsA + (rA * 8 + ((ks * 4 + quad) ^ (rA & 7))) * 16);
          int rB = dh * 64 + t4 * 16 + col16;
          bf[t4] = *(const short8*)(ldsB + (rB * 8 + ((ks * 4 + quad) ^ (rB & 7))) * 16);
        }
#pragma unroll
        for (int mt = 0; mt < 4; ++mt)
#pragma unroll
          for (int dt = 0; dt < 4; ++dt)
            acc[mt][dt] = __builtin_amdgcn_mfma_f32_16x16x32_bf16(af[mt], bf[dt], acc[mt][dt], 0, 0, 0);
      }
    }
    // epilogue: gate * (acc [+ b2]) -> atomicAdd scatter (4 adds total per out element)
    float b2v[4];
#pragma unroll
    for (int dt = 0; dt < 4; ++dt)
      b2v[dt] = addb2 ? b2[e * DD + ntile * 128 + dh * 64 + dt * 16 + col16] : 0.f;
#pragma unroll
    for (int mt = 0; mt < 4; ++mt) {
#pragma unroll
      for (int r = 0; r < 4; ++r) {
        int idx = mtile * 128 + mh * 64 + mt * 16 + quad * 4 + r;
        if (idx < cnt) {
          int tok = lists[e * TT + idx];
          float g = gates[e * TT + idx];
          float* orow = out + (size_t)tok * DD + ntile * 128;
#pragma unroll
          for (int dt = 0; dt < 4; ++dt)
            atomicAdd(orow + dh * 64 + dt * 16 + col16, g * (acc[mt][dt][r] + b2v[dt]));
        }
      }
    }
  }
}

// ---------------- fallback fused MLP (round-1 kernel, used only if ws too small) ----------------
#define XS_OFF   0
#define W1S_OFF  65536
#define W2S_OFF  81920
#define HS_OFF   147456
#define TOK_OFF  155648
#define GATE_OFF 155904

__global__ __launch_bounds__(512, 1)
void moe_mlp(const u16* __restrict__ xb, const u16* __restrict__ w1t,
             const u16* __restrict__ w2t, const float* __restrict__ b1,
             const float* __restrict__ b2, const int* __restrict__ counts,
             const int* __restrict__ lists, const float* __restrict__ gates,
             float* __restrict__ out) {
  __shared__ __align__(16) char smem[156160];
  short8* xs  = (short8*)(smem + XS_OFF);
  short8* w1s = (short8*)(smem + W1S_OFF);
  short8* w2s = (short8*)(smem + W2S_OFF);
  short8* hs  = (short8*)(smem + HS_OFF);
  int*   tok_s  = (int*)(smem + TOK_OFF);
  float* gate_s = (float*)(smem + GATE_OFF);

  const int e = blockIdx.x >> 9;
  const int tile = blockIdx.x & 511;
  const int cnt = counts[e];
  if (tile * 64 >= cnt) return;

  const int tid = threadIdx.x;
  const int lane = tid & 63;
  const int w = tid >> 6;
  const int col = lane & 15;
  const int quad = lane >> 4;

  if (tid < 64) {
    int idx = tile * 64 + tid;
    int tok = -1; float g = 0.f;
    if (idx < cnt) { tok = lists[e * TT + idx]; g = gates[e * TT + idx]; }
    tok_s[tid] = tok; gate_s[tid] = g;
  }
  __syncthreads();

#pragma unroll
  for (int it = 0; it < 8; ++it) {
    int c = it * 512 + tid;
    int m16 = c & 15, d8 = (c >> 4) & 63, mt = c >> 10;
    int tok = tok_s[mt * 16 + m16];
    short8 v = {0, 0, 0, 0, 0, 0, 0, 0};
    if (tok >= 0) v = *(const short8*)(xb + ((size_t)tok * DD + d8 * 8));
    xs[c] = v;
  }

  floatx4 acc2[16];
#pragma unroll
  for (int i = 0; i < 16; ++i) acc2[i] = (floatx4){0.f, 0.f, 0.f, 0.f};

  const int htile = w & 3, mhalf = w >> 2;
  const int mtile2 = w & 3, nhalf = w >> 2;

  for (int hc = 0; hc < 32; ++hc) {
    floatx4 acc1[2];
    acc1[0] = (floatx4){0.f, 0.f, 0.f, 0.f};
    acc1[1] = (floatx4){0.f, 0.f, 0.f, 0.f};
    for (int dc = 0; dc < 4; ++dc) {
      __syncthreads();
      {
        int c = tid;
        int h16 = c & 15, d16 = (c >> 4) & 7, nt = (c >> 7) & 3;
        const short8* gp = (const short8*)(w1t +
            ((size_t)(e * HH + hc * 64 + nt * 16 + h16) * DD + dc * 128 + d16 * 16));
        short8 v0 = gp[0], v1 = gp[1];
        int a0 = nt * 256 + (d16 >> 1) * 64 + (d16 & 1) * 32 + h16;
        w1s[a0] = v0; w1s[a0 + 16] = v1;
      }
      __syncthreads();
#pragma unroll
      for (int ks = 0; ks < 4; ++ks) {
        short8 af = w1s[(htile * 4 + ks) * 64 + lane];
#pragma unroll
        for (int mt = 0; mt < 2; ++mt) {
          short8 bf = xs[((mhalf * 2 + mt) * 16 + dc * 4 + ks) * 64 + lane];
          acc1[mt] = __builtin_amdgcn_mfma_f32_16x16x32_bf16(af, bf, acc1[mt], 0, 0, 0);
        }
      }
    }
    {
      int hloc = htile * 16 + quad * 4;
      float b1v[4];
#pragma unroll
      for (int r = 0; r < 4; ++r) b1v[r] = b1[e * HH + hc * 64 + hloc + r];
#pragma unroll
      for (int nt = 0; nt < 2; ++nt) {
        int m = mhalf * 32 + nt * 16 + col;
        u64 pk = 0;
#pragma unroll
        for (int r = 0; r < 4; ++r) {
          float f = acc1[nt][r] + b1v[r];
          f = fmaxf(f, 0.f);
          pk |= (u64)f2bf(f) << (16 * r);
        }
        int kblock = htile >> 1;
        int quadp = (htile & 1) * 2 + (quad >> 1);
        *(u64*)((char*)hs +
            (((m >> 4) * 2 + kblock) * 64 + ((m & 15) + 16 * quadp)) * 16 + (quad & 1) * 8) = pk;
      }
    }
    __syncthreads();
#pragma unroll
    for (int it = 0; it < 4; ++it) {
      int c = it * 512 + tid;
      int n16 = c & 15, hq = (c >> 4) & 3, nt = (c >> 6) & 31;
      const short8* gp = (const short8*)(w2t +
          ((size_t)(e * DD + nt * 16 + n16) * HH + hc * 64 + hq * 16));
      short8 v0 = gp[0], v1 = gp[1];
      int a0 = nt * 128 + (hq >> 1) * 64 + (hq & 1) * 32 + n16;
      w2s[a0] = v0; w2s[a0 + 16] = v1;
    }
    __syncthreads();
#pragma unroll
    for (int ks = 0; ks < 2; ++ks) {
      short8 af = hs[(mtile2 * 2 + ks) * 64 + lane];
#pragma unroll
      for (int nt = 0; nt < 16; ++nt) {
        short8 bf = w2s[((nhalf * 16 + nt) * 2 + ks) * 64 + lane];
        acc2[nt] = __builtin_amdgcn_mfma_f32_16x16x32_bf16(af, bf, acc2[nt], 0, 0, 0);
      }
    }
  }

#pragma unroll
  for (int r = 0; r < 4; ++r) {
    int m = mtile2 * 16 + quad * 4 + r;
    int tok = tok_s[m];
    if (tok < 0) continue;
    float g = gate_s[m];
    float* orow = out + (size_t)tok * DD;
#pragma unroll
    for (int nt = 0; nt < 16; ++nt) {
      int n = nhalf * 256 + nt * 16 + col;
      atomicAdd(orow + n, g * (acc2[nt][r] + b2[e * DD + n]));
    }
  }
}

extern "C" void kernel_launch(void* const* d_in, const int* in_sizes, int n_in,
                              void* d_out, int out_size, void* d_ws, size_t ws_size,
                              hipStream_t stream) {
  const float* x     = (const float*)d_in[0];
  const float* noise = (const float*)d_in[1];
  const float* Wg    = (const float*)d_in[2];
  const float* bg    = (const float*)d_in[3];
  const float* Wn    = (const float*)d_in[4];
  const float* bn    = (const float*)d_in[5];
  const float* W1    = (const float*)d_in[6];
  const float* b1    = (const float*)d_in[7];
  const float* W2    = (const float*)d_in[8];
  const float* b2    = (const float*)d_in[9];
  float* out = (float*)d_out;
  char* ws = (char*)d_ws;

  // ws layout
  u16*  w1t    = (u16*)(ws + 0x0000000);   // [E][H][D] bf16, 16 MB
  u16*  w2t    = (u16*)(ws + 0x1000000);   // [E][D][H] bf16, 16 MB
  u16*  xb     = (u16*)(ws + 0x2000000);   // [T][D] bf16, 32 MB
  int*  counts = (int*)(ws + 0x4000000);   // [E]
  int*  lists  = (int*)(ws + 0x4001000);   // [E][T] int, 1 MB
  float* gatesp= (float*)(ws + 0x4101000); // [E][T] f32, 1 MB
  int*  topk_i = (int*)(ws + 0x4201000);   // [T]
  float* tg0   = (float*)(ws + 0x4221000); // [T]
  float* tg1   = (float*)(ws + 0x4241000); // [T]
  u16*  Hbuf   = (u16*)(ws + 0x4300000);   // [2*TT + 128][HC] bf16 = 134.48 MB
  const size_t ws_needed = 0x4300000ull + (size_t)(2 * TT + 128) * HC * 2;  // 204,734,464

  hipMemsetAsync(out, 0, (size_t)TT * DD * 4, stream);
  hipMemsetAsync(counts, 0, EE * 4, stream);
  convert_x_kernel<<<TT * DD / 4 / 256, 256, 0, stream>>>(x, xb, TT * DD / 4);
  transpose_bf16<<<dim3(HH / 32, DD / 32, EE), dim3(32, 8), 0, stream>>>(W1, w1t, DD, HH);
  transpose_bf16<<<dim3(DD / 32, HH / 32, EE), dim3(32, 8), 0, stream>>>(W2, w2t, HH, DD);
  router_topk<<<TT / 4, 256, 0, stream>>>(x, noise, Wg, bg, Wn, bn, topk_i, tg0, tg1);
  router_bin<<<TT / 256, 256, 0, stream>>>(topk_i, tg0, tg1, counts, lists, gatesp);

  if (ws_size >= ws_needed) {
    // chunk 0: h in [0, HC)
    pass1_gemm<<<dim3(640, HC / 128), 256, 0, stream>>>(xb, w1t, b1, counts, lists, Hbuf, 0);
    pass2_gemm<<<dim3(640, 4), 256, 0, stream>>>(Hbuf, w2t, b2, counts, lists, gatesp, out, 0, 1);
    // chunk 1: h in [HC, 2*HC)
    pass1_gemm<<<dim3(640, HC / 128), 256, 0, stream>>>(xb, w1t, b1, counts, lists, Hbuf, HC);
    pass2_gemm<<<dim3(640, 4), 256, 0, stream>>>(Hbuf, w2t, b2, counts, lists, gatesp, out, HC, 0);
  } else {
    moe_mlp<<<EE * 512, 512, 0, stream>>>(xb, w1t, w2t, b1, b2, counts, lists, gatesp, out);
  }
}

// Round 4
// 846.631 us; speedup vs baseline: 2.5997x; 1.0402x over previous
//
#include <hip/hip_runtime.h>

#define TT 32768   // B*S tokens
#define DD 512
#define HH 2048
#define EE 8
#define HC 1024    // h-chunk: H buffer is [2*TT+128][HC] bf16 per chunk pass

typedef unsigned short u16;
typedef unsigned int u32;
typedef unsigned long long u64;
using short8  = __attribute__((ext_vector_type(8))) short;
using floatx4 = __attribute__((ext_vector_type(4))) float;

__device__ __forceinline__ u16 f2bf(float f) {
  unsigned u = __float_as_uint(f);
  u += 0x7FFFu + ((u >> 16) & 1u);   // RNE; inputs are finite
  return (u16)(u >> 16);
}

// async global->LDS, 16B per lane; lds dest is wave-uniform base + lane*16
__device__ __forceinline__ void gl2lds16(const u16* g, char* l) {
  __builtin_amdgcn_global_load_lds(
      (const __attribute__((address_space(1))) u32*)(const void*)g,
      (__attribute__((address_space(3))) u32*)(void*)l, 16, 0, 0);
}

// ------------- transpose fp32 [E][R][C] -> bf16 [E][C][R] -------------
__global__ void transpose_bf16(const float* __restrict__ in, u16* __restrict__ out, int R, int C) {
  __shared__ float tile[32][33];
  int e = blockIdx.z;
  const float* src = in + (size_t)e * R * C;
  u16* dst = out + (size_t)e * R * C;
  int tx = threadIdx.x, ty = threadIdx.y;
  int c0 = blockIdx.x * 32, r0 = blockIdx.y * 32;
#pragma unroll
  for (int i = 0; i < 32; i += 8)
    tile[ty + i][tx] = src[(size_t)(r0 + ty + i) * C + c0 + tx];
  __syncthreads();
#pragma unroll
  for (int i = 0; i < 32; i += 8)
    dst[(size_t)(c0 + ty + i) * R + r0 + tx] = f2bf(tile[tx][ty + i]);
}

// ------- router pass 1: one wave per token; also emits bf16 x row (fused convert) -------
__global__ void router_topk(const float* __restrict__ x, const float* __restrict__ noise,
                            const float* __restrict__ Wg, const float* __restrict__ bg,
                            const float* __restrict__ Wn, const float* __restrict__ bn,
                            u16* __restrict__ xb, int* __restrict__ topk_i,
                            float* __restrict__ topk_g0, float* __restrict__ topk_g1) {
  const int t = (blockIdx.x * blockDim.x + threadIdx.x) >> 6;
  const int lane = threadIdx.x & 63;
  if (t >= TT) return;
  const float4* xr = (const float4*)(x + (size_t)t * DD) + lane * 2;
  float4 xa = xr[0], xbv = xr[1];
  float xv[8] = {xa.x, xa.y, xa.z, xa.w, xbv.x, xbv.y, xbv.z, xbv.w};
  // fused fp32->bf16 convert of x (wave already holds the whole row)
  {
    ushort4 o0, o1;
    o0.x = f2bf(xa.x); o0.y = f2bf(xa.y); o0.z = f2bf(xa.z); o0.w = f2bf(xa.w);
    o1.x = f2bf(xbv.x); o1.y = f2bf(xbv.y); o1.z = f2bf(xbv.z); o1.w = f2bf(xbv.w);
    ushort4* xo = (ushort4*)(xb + (size_t)t * DD) + lane * 2;
    xo[0] = o0; xo[1] = o1;
  }
  float pg[8], pn[8];
#pragma unroll
  for (int e = 0; e < 8; ++e) { pg[e] = 0.f; pn[e] = 0.f; }
  const float4* wg4 = (const float4*)(Wg + lane * 64);
  const float4* wn4 = (const float4*)(Wn + lane * 64);
#pragma unroll
  for (int j = 0; j < 8; ++j) {
    float xj = xv[j];
    float4 a = wg4[2 * j], b = wg4[2 * j + 1];
    pg[0] += xj * a.x; pg[1] += xj * a.y; pg[2] += xj * a.z; pg[3] += xj * a.w;
    pg[4] += xj * b.x; pg[5] += xj * b.y; pg[6] += xj * b.z; pg[7] += xj * b.w;
    a = wn4[2 * j]; b = wn4[2 * j + 1];
    pn[0] += xj * a.x; pn[1] += xj * a.y; pn[2] += xj * a.z; pn[3] += xj * a.w;
    pn[4] += xj * b.x; pn[5] += xj * b.y; pn[6] += xj * b.z; pn[7] += xj * b.w;
  }
#pragma unroll
  for (int off = 32; off; off >>= 1) {
#pragma unroll
    for (int e = 0; e < 8; ++e) {
      pg[e] += __shfl_xor(pg[e], off);
      pn[e] += __shfl_xor(pn[e], off);
    }
  }
  if (lane == 0) {
    float noisy[8];
#pragma unroll
    for (int e = 0; e < 8; ++e) {
      float nl = pn[e] + bn[e];
      float sp = (nl > 20.f) ? nl : log1pf(expf(nl));
      noisy[e] = pg[e] + bg[e] + noise[(size_t)t * EE + e] * sp;
    }
    int i0 = 0; float v0 = noisy[0];
#pragma unroll
    for (int e = 1; e < 8; ++e) if (noisy[e] > v0) { v0 = noisy[e]; i0 = e; }
    int i1 = -1; float v1 = -3.4e38f;
#pragma unroll
    for (int e = 0; e < 8; ++e) if (e != i0 && noisy[e] > v1) { v1 = noisy[e]; i1 = e; }
    float ed = expf(v1 - v0);
    float inv = 1.f / (1.f + ed);
    topk_i[t] = i0 | (i1 << 8);
    topk_g0[t] = inv;
    topk_g1[t] = ed * inv;
  }
}

// ---------------- router pass 2: bin tokens; 8 global atomics per 256 tokens ----------------
__global__ void router_bin(const int* __restrict__ topk_i, const float* __restrict__ tg0,
                           const float* __restrict__ tg1, int* __restrict__ counts,
                           int* __restrict__ lists, float* __restrict__ gates) {
  __shared__ int hist[EE], base_s[EE];
  int t = blockIdx.x * 256 + threadIdx.x;
  if (threadIdx.x < EE) hist[threadIdx.x] = 0;
  __syncthreads();
  int p = topk_i[t];
  int i0 = p & 255, i1 = p >> 8;
  int r0 = atomicAdd(&hist[i0], 1);
  int r1 = atomicAdd(&hist[i1], 1);
  __syncthreads();
  if (threadIdx.x < EE)
    base_s[threadIdx.x] = atomicAdd(&counts[threadIdx.x], hist[threadIdx.x]);
  __syncthreads();
  int s0 = base_s[i0] + r0, s1 = base_s[i1] + r1;
  lists[i0 * TT + s0] = t; gates[i0 * TT + s0] = tg0[t];
  lists[i1 * TT + s1] = t; gates[i1 * TT + s1] = tg1[t];
}

// ============ PASS 1: H_chunk = relu(X_gathered @ W1[:, hoff:hoff+HC] + b1)  (bf16) ============
// m97 structure: 128x128 tile, BK=64, 4 waves x (64x64), XOR-swizzled 16B LDS chunks.
// Persistent: grid x = 8 experts * MS1 seeds; each block walks m-tiles with stride MS1.
#define MS1 12
#define MS2 24
__global__ __launch_bounds__(256, 2)
void pass1_gemm(const u16* __restrict__ xb, const u16* __restrict__ w1t,
                const float* __restrict__ b1, const int* __restrict__ counts,
                const int* __restrict__ lists, u16* __restrict__ H, int hoff) {
  __shared__ __align__(16) char lds[32768];
  char* ldsA = lds;           // W1^T tile [128 h][64 k]
  char* ldsB = lds + 16384;   // X tile    [128 m][64 k]
  const int e = blockIdx.x & 7;           // expert -> XCD pin for L2 locality
  const int mseed = blockIdx.x >> 3;      // 0..MS1-1
  const int ntile = blockIdx.y;           // 0..HC/128-1
  const int cnt = counts[e];
  int eOff = 0;
#pragma unroll
  for (int j = 0; j < EE; ++j) eOff += (j < e) ? counts[j] : 0;
  const int tid = threadIdx.x, lane = tid & 63, w = tid >> 6;
  const int col16 = lane & 15, quad = lane >> 4;
  const int hh = w & 1, mh = w >> 1;

  int rowi[4], kqi[4];
  const u16* wptr[4];
#pragma unroll
  for (int i = 0; i < 4; ++i) {
    int c = tid + i * 256;
    rowi[i] = c >> 3;
    kqi[i] = (c & 7) ^ (rowi[i] & 7);
    wptr[i] = w1t + (size_t)(e * HH + hoff + ntile * 128 + rowi[i]) * DD + kqi[i] * 8;
  }

  for (int mtile = mseed; mtile * 128 < cnt; mtile += MS1) {
    const u16* xptr[4];
#pragma unroll
    for (int i = 0; i < 4; ++i) {
      int idx = mtile * 128 + rowi[i];
      int tok = (idx < cnt) ? lists[e * TT + idx] : 0;
      xptr[i] = xb + (size_t)tok * DD + kqi[i] * 8;
    }
    floatx4 acc[4][4];
#pragma unroll
    for (int a = 0; a < 4; ++a)
#pragma unroll
      for (int b = 0; b < 4; ++b) acc[a][b] = (floatx4){0.f, 0.f, 0.f, 0.f};

    for (int kc = 0; kc < 8; ++kc) {      // K = 512, BK = 64
      __syncthreads();
#pragma unroll
      for (int i = 0; i < 4; ++i) {
        int off = (tid + i * 256) * 16;
        gl2lds16(wptr[i] + kc * 64, ldsA + off);
        gl2lds16(xptr[i] + kc * 64, ldsB + off);
      }
      __syncthreads();
#pragma unroll
      for (int ks = 0; ks < 2; ++ks) {
        short8 af[4], bf[4];
#pragma unroll
        for (int t4 = 0; t4 < 4; ++t4) {
          int rA = hh * 64 + t4 * 16 + col16;
          af[t4] = *(const short8*)(ldsA + (rA * 8 + ((ks * 4 + quad) ^ (rA & 7))) * 16);
          int rB = mh * 64 + t4 * 16 + col16;
          bf[t4] = *(const short8*)(ldsB + (rB * 8 + ((ks * 4 + quad) ^ (rB & 7))) * 16);
        }
#pragma unroll
        for (int ht = 0; ht < 4; ++ht)
#pragma unroll
          for (int mt = 0; mt < 4; ++mt)
            acc[ht][mt] = __builtin_amdgcn_mfma_f32_16x16x32_bf16(af[ht], bf[mt], acc[ht][mt], 0, 0, 0);
      }
    }
    // epilogue: +b1, relu, bf16 pack (4 consecutive h per lane -> b64 store into H chunk)
#pragma unroll
    for (int ht = 0; ht < 4; ++ht) {
      int hloc = ntile * 128 + hh * 64 + ht * 16 + quad * 4;   // within chunk
      float b1v[4];
#pragma unroll
      for (int r = 0; r < 4; ++r) b1v[r] = b1[e * HH + hoff + hloc + r];
#pragma unroll
      for (int mt = 0; mt < 4; ++mt) {
        int gm = mtile * 128 + mh * 64 + mt * 16 + col16;
        if (gm < cnt) {
          u64 pk = 0;
#pragma unroll
          for (int r = 0; r < 4; ++r) {
            float f = fmaxf(acc[ht][mt][r] + b1v[r], 0.f);
            pk |= (u64)f2bf(f) << (16 * r);
          }
          *(u64*)(H + (size_t)(eOff + gm) * HC + hloc) = pk;
        }
      }
    }
  }
}

// ============ PASS 2: out += gate * (H_chunk @ W2[hoff:hoff+HC, :] [+ b2]) ============
__global__ __launch_bounds__(256, 2)
void pass2_gemm(const u16* __restrict__ H, const u16* __restrict__ w2t,
                const float* __restrict__ b2, const int* __restrict__ counts,
                const int* __restrict__ lists, const float* __restrict__ gates,
                float* __restrict__ out, int hoff, int addb2) {
  __shared__ __align__(16) char lds[32768];
  char* ldsA = lds;           // H tile   [128 m][64 k]
  char* ldsB = lds + 16384;   // W2^T tile[128 d][64 k]
  const int e = blockIdx.x & 7;
  const int mseed = blockIdx.x >> 3;      // 0..MS2-1
  const int ntile = blockIdx.y;           // 0..3 (d block of 128)
  const int cnt = counts[e];
  int eOff = 0;
#pragma unroll
  for (int j = 0; j < EE; ++j) eOff += (j < e) ? counts[j] : 0;
  const int tid = threadIdx.x, lane = tid & 63, w = tid >> 6;
  const int col16 = lane & 15, quad = lane >> 4;
  const int mh = w & 1, dh = w >> 1;

  int rowi[4], kqi[4];
  const u16* wptr[4];
#pragma unroll
  for (int i = 0; i < 4; ++i) {
    int c = tid + i * 256;
    rowi[i] = c >> 3;
    kqi[i] = (c & 7) ^ (rowi[i] & 7);
    wptr[i] = w2t + (size_t)(e * DD + ntile * 128 + rowi[i]) * HH + hoff + kqi[i] * 8;
  }

  for (int mtile = mseed; mtile * 128 < cnt; mtile += MS2) {
    const u16* hptr[4];
#pragma unroll
    for (int i = 0; i < 4; ++i)
      hptr[i] = H + (size_t)(eOff + mtile * 128 + rowi[i]) * HC + kqi[i] * 8;  // pad rows exist

    floatx4 acc[4][4];
#pragma unroll
    for (int a = 0; a < 4; ++a)
#pragma unroll
      for (int b = 0; b < 4; ++b) acc[a][b] = (floatx4){0.f, 0.f, 0.f, 0.f};

    for (int kc = 0; kc < HC / 64; ++kc) {   // K = HC = 1024, BK = 64
      __syncthreads();
#pragma unroll
      for (int i = 0; i < 4; ++i) {
        int off = (tid + i * 256) * 16;
        gl2lds16(hptr[i] + kc * 64, ldsA + off);
        gl2lds16(wptr[i] + kc * 64, ldsB + off);
      }
      __syncthreads();
#pragma unroll
      for (int ks = 0; ks < 2; ++ks) {
        short8 af[4], bf[4];
#pragma unroll
        for (int t4 = 0; t4 < 4; ++t4) {
          int rA = mh * 64 + t4 * 16 + col16;
          af[t4] = *(const short8*)(ldsA + (rA * 8 + ((ks * 4 + quad) ^ (rA & 7))) * 16);
          int rB = dh * 64 + t4 * 16 + col16;
          bf[t4] = *(const short8*)(ldsB + (rB * 8 + ((ks * 4 + quad) ^ (rB & 7))) * 16);
        }
#pragma unroll
        for (int mt = 0; mt < 4; ++mt)
#pragma unroll
          for (int dt = 0; dt < 4; ++dt)
            acc[mt][dt] = __builtin_amdgcn_mfma_f32_16x16x32_bf16(af[mt], bf[dt], acc[mt][dt], 0, 0, 0);
      }
    }
    // epilogue: gate * (acc [+ b2]) -> atomicAdd scatter (4 adds total per out element)
    float b2v[4];
#pragma unroll
    for (int dt = 0; dt < 4; ++dt)
      b2v[dt] = addb2 ? b2[e * DD + ntile * 128 + dh * 64 + dt * 16 + col16] : 0.f;
#pragma unroll
    for (int mt = 0; mt < 4; ++mt) {
#pragma unroll
      for (int r = 0; r < 4; ++r) {
        int idx = mtile * 128 + mh * 64 + mt * 16 + quad * 4 + r;
        if (idx < cnt) {
          int tok = lists[e * TT + idx];
          float g = gates[e * TT + idx];
          float* orow = out + (size_t)tok * DD + ntile * 128;
#pragma unroll
          for (int dt = 0; dt < 4; ++dt)
            atomicAdd(orow + dh * 64 + dt * 16 + col16, g * (acc[mt][dt][r] + b2v[dt]));
        }
      }
    }
  }
}

extern "C" void kernel_launch(void* const* d_in, const int* in_sizes, int n_in,
                              void* d_out, int out_size, void* d_ws, size_t ws_size,
                              hipStream_t stream) {
  const float* x     = (const float*)d_in[0];
  const float* noise = (const float*)d_in[1];
  const float* Wg    = (const float*)d_in[2];
  const float* bg    = (const float*)d_in[3];
  const float* Wn    = (const float*)d_in[4];
  const float* bn    = (const float*)d_in[5];
  const float* W1    = (const float*)d_in[6];
  const float* b1    = (const float*)d_in[7];
  const float* W2    = (const float*)d_in[8];
  const float* b2    = (const float*)d_in[9];
  float* out = (float*)d_out;
  char* ws = (char*)d_ws;

  // ws layout
  u16*  w1t    = (u16*)(ws + 0x0000000);   // [E][H][D] bf16, 16 MB
  u16*  w2t    = (u16*)(ws + 0x1000000);   // [E][D][H] bf16, 16 MB
  u16*  xb     = (u16*)(ws + 0x2000000);   // [T][D] bf16, 32 MB
  int*  counts = (int*)(ws + 0x4000000);   // [E]
  int*  lists  = (int*)(ws + 0x4001000);   // [E][T] int, 1 MB
  float* gatesp= (float*)(ws + 0x4101000); // [E][T] f32, 1 MB
  int*  topk_i = (int*)(ws + 0x4201000);   // [T]
  float* tg0   = (float*)(ws + 0x4221000); // [T]
  float* tg1   = (float*)(ws + 0x4241000); // [T]
  u16*  Hbuf   = (u16*)(ws + 0x4300000);   // [2*TT + 128][HC] bf16 = 134.48 MB
  const size_t ws_needed = 0x4300000ull + (size_t)(2 * TT + 128) * HC * 2;  // 204,734,464
  (void)ws_needed; (void)ws_size;

  hipMemsetAsync(out, 0, (size_t)TT * DD * 4, stream);
  hipMemsetAsync(counts, 0, EE * 4, stream);
  transpose_bf16<<<dim3(HH / 32, DD / 32, EE), dim3(32, 8), 0, stream>>>(W1, w1t, DD, HH);
  transpose_bf16<<<dim3(DD / 32, HH / 32, EE), dim3(32, 8), 0, stream>>>(W2, w2t, HH, DD);
  router_topk<<<TT / 4, 256, 0, stream>>>(x, noise, Wg, bg, Wn, bn, xb, topk_i, tg0, tg1);
  router_bin<<<TT / 256, 256, 0, stream>>>(topk_i, tg0, tg1, counts, lists, gatesp);

  // chunk 0: h in [0, HC)
  pass1_gemm<<<dim3(8 * MS1, HC / 128), 256, 0, stream>>>(xb, w1t, b1, counts, lists, Hbuf, 0);
  pass2_gemm<<<dim3(8 * MS2, 4), 256, 0, stream>>>(Hbuf, w2t, b2, counts, lists, gatesp, out, 0, 1);
  // chunk 1: h in [HC, 2*HC)
  pass1_gemm<<<dim3(8 * MS1, HC / 128), 256, 0, stream>>>(xb, w1t, b1, counts, lists, Hbuf, HC);
  pass2_gemm<<<dim3(8 * MS2, 4), 256, 0, stream>>>(Hbuf, w2t, b2, counts, lists, gatesp, out, HC, 0);
}